// Round 3
// baseline (38.170 us; speedup 1.0000x reference)
//
#include <hip/hip_runtime.h>
#include <hip/hip_bf16.h>

typedef __attribute__((ext_vector_type(8))) short short8;
typedef __attribute__((ext_vector_type(4))) float f32x4;
typedef __attribute__((ext_vector_type(16))) float f32x16;

#define NROWS 65536             // BATCH * N_EDGES
#define EDGE_DIM 64
#define NODE_DIM 32
#define NN 1024                 // NODE_DIM^2

__device__ __forceinline__ short f2bf(float f) {
    unsigned u = __builtin_bit_cast(unsigned, f);
    u += 0x7FFFu + ((u >> 16) & 1u);            // round-to-nearest-even
    return (short)(u >> 16);
}

// Pack W [64,1024] f32 -> bf16 A-operand fragments for mfma_f32_32x32x16_bf16.
// frag id = i*4 + ks (i = output row 0..31, ks = K-step 0..3).
// Wb[(frag*64 + l)*8 + t] = bf16(W[ks*16 + (l>>5)*8 + t, i*32 + (l&31)])
// (A row m = A-column c = l&31; k = (l>>5)*8 + t — same symmetric k-map as B.)
__global__ void prep_W(const float* __restrict__ W, short* __restrict__ Wb) {
    int frag = blockIdx.x * 4 + (threadIdx.x >> 6);   // 32 blocks x 4 waves
    int l = threadIdx.x & 63;
    int col = (frag >> 2) * 32 + (l & 31);
    int fb = (frag & 3) * 16 + ((l >> 5) * 8);
    short8 v;
#pragma unroll
    for (int t = 0; t < 8; ++t)
        v[t] = f2bf(W[(size_t)(fb + t) * NN + col]);
    *reinterpret_cast<short8*>(Wb + ((size_t)frag * 64 + l) * 8) = v;
}

// One wave = 32 edges (MFMA N). Per output row i: one 32x32x64 product via
// 4 chained mfma_32x32x16 (M = 32 A-columns = all j). W fragments read
// directly from L2-resident Wb (coalesced dwordx4) — NO LDS staging, NO
// barriers anywhere. Bias enters as the C-operand. Epilogue: relu+matvec in
// f32 (16 fma/lane), one shfl_xor(32), out restaged through LDS for
// fully-coalesced float4 stores.
__global__ __launch_bounds__(256, 2) void mp_main(
    const float* __restrict__ node, const float* __restrict__ edge,
    const short* __restrict__ Wb, const float* __restrict__ bias,
    float* __restrict__ out) {
    __shared__ __align__(16) float ldsO[4][32][33];   // per-wave 32x32 out tile

    const int tid = threadIdx.x;
    const int wid = tid >> 6;
    const int l   = tid & 63;
    const int e32 = l & 31;                  // lane's edge col (MFMA N)
    const int h   = l >> 5;                  // lane half (k-group / row offset)
    const int eb  = blockIdx.x * 128 + wid * 32;
    const int e   = eb + e32;

    // ---- edge B-fragments: ef[ks], k = h*8 + t -> edge[e, ks*16 + h*8 + t]
    short8 ef[4];
    const float* erow = edge + (size_t)e * EDGE_DIM;
#pragma unroll
    for (int ks = 0; ks < 4; ++ks) {
        float4 a = *reinterpret_cast<const float4*>(erow + ks * 16 + h * 8);
        float4 b = *reinterpret_cast<const float4*>(erow + ks * 16 + h * 8 + 4);
        short8 v;
        v[0] = f2bf(a.x); v[1] = f2bf(a.y); v[2] = f2bf(a.z); v[3] = f2bf(a.w);
        v[4] = f2bf(b.x); v[5] = f2bf(b.y); v[6] = f2bf(b.z); v[7] = f2bf(b.w);
        ef[ks] = v;
    }

    // ---- node values this lane needs: acc reg r -> j = (r&3) + 8*(r>>2) + 4*h
    float nv[16];
    const float* nrow = node + (size_t)e * NODE_DIM;
#pragma unroll
    for (int q = 0; q < 4; ++q) {
        float4 n = *reinterpret_cast<const float4*>(nrow + q * 8 + h * 4);
        nv[q * 4 + 0] = n.x; nv[q * 4 + 1] = n.y;
        nv[q * 4 + 2] = n.z; nv[q * 4 + 3] = n.w;
    }

#pragma unroll 4
    for (int i = 0; i < 32; ++i) {
        const short* wp = Wb + (size_t)i * 2048;      // 4 frags x 512 shorts
        short8 w0 = *reinterpret_cast<const short8*>(wp + 0 * 512 + l * 8);
        short8 w1 = *reinterpret_cast<const short8*>(wp + 1 * 512 + l * 8);
        short8 w2 = *reinterpret_cast<const short8*>(wp + 2 * 512 + l * 8);
        short8 w3 = *reinterpret_cast<const short8*>(wp + 3 * 512 + l * 8);

        // bias as C-init: reg r=q*4+rr -> row q*8 + h*4 + rr (contiguous per q)
        f32x16 acc;
#pragma unroll
        for (int q = 0; q < 4; ++q) {
            float4 bq = *reinterpret_cast<const float4*>(bias + i * 32 + q * 8 + h * 4);
            acc[q * 4 + 0] = bq.x; acc[q * 4 + 1] = bq.y;
            acc[q * 4 + 2] = bq.z; acc[q * 4 + 3] = bq.w;
        }

        acc = __builtin_amdgcn_mfma_f32_32x32x16_bf16(w0, ef[0], acc, 0, 0, 0);
        acc = __builtin_amdgcn_mfma_f32_32x32x16_bf16(w1, ef[1], acc, 0, 0, 0);
        acc = __builtin_amdgcn_mfma_f32_32x32x16_bf16(w2, ef[2], acc, 0, 0, 0);
        acc = __builtin_amdgcn_mfma_f32_32x32x16_bf16(w3, ef[3], acc, 0, 0, 0);

        // relu + matvec: lane covers 16 of 32 j's; other half via shfl_xor(32)
        float p = 0.f;
#pragma unroll
        for (int r = 0; r < 16; ++r)
            p += fmaxf(acc[r], 0.f) * nv[r];
        p += __shfl_xor(p, 32);
        if (l < 32) ldsO[wid][l][i] = p;              // msg[e = eb + l, i]
    }

    // ---- coalesced store: wave tile = 32 rows x 128 B contiguous
#pragma unroll
    for (int q = 0; q < 4; ++q) {
        int idx = q * 64 + l;                          // 16B chunk in 4 KB tile
        float4 v = *reinterpret_cast<const float4*>(&ldsO[wid][idx >> 3][(idx & 7) * 4]);
        *reinterpret_cast<float4*>(out + (size_t)eb * NODE_DIM + (size_t)idx * 4) = v;
    }
}

extern "C" void kernel_launch(void* const* d_in, const int* in_sizes, int n_in,
                              void* d_out, int out_size, void* d_ws, size_t ws_size,
                              hipStream_t stream) {
    const float* node = (const float*)d_in[0];  // [16,4096,32] f32
    const float* edge = (const float*)d_in[1];  // [16,4096,64] f32
    const float* W    = (const float*)d_in[2];  // [64,1024] f32
    const float* bias = (const float*)d_in[3];  // [1024] f32
    float* out = (float*)d_out;                 // [16,4096,32] f32
    short* Wb = (short*)d_ws;                   // 128 KB bf16 fragment-packed W

    prep_W<<<dim3(32), dim3(256), 0, stream>>>(W, Wb);
    mp_main<<<dim3(NROWS / 128), dim3(256), 0, stream>>>(node, edge, Wb, bias, out);
}

// Round 5
// 35.036 us; speedup vs baseline: 1.0895x; 1.0895x over previous
//
#include <hip/hip_runtime.h>
#include <hip/hip_bf16.h>

typedef __attribute__((ext_vector_type(8))) short short8;
typedef __attribute__((ext_vector_type(4))) float f32x4;
typedef __attribute__((ext_vector_type(16))) float f32x16;

#define NROWS 65536             // BATCH * N_EDGES
#define EDGE_DIM 64
#define NODE_DIM 32
#define NN 1024                 // NODE_DIM^2

__device__ __forceinline__ short f2bf(float f) {
    unsigned u = __builtin_bit_cast(unsigned, f);
    u += 0x7FFFu + ((u >> 16) & 1u);            // round-to-nearest-even
    return (short)(u >> 16);
}

// Pack W [64,1024] f32 -> bf16 A-operand fragments for mfma_f32_32x32x16_bf16.
// frag id = i*4 + ks (i = output row 0..31, ks = K-step 0..3).
// Wb[(frag*64 + l)*8 + t] = bf16(W[ks*16 + (l>>5)*8 + t, i*32 + (l&31)])
// (symmetric (lane-half,slot)->k map, identical to the B-operand pack; only
// the HW-verified C/D layout is load-bearing. Verified correct in R2/R3.)
__global__ void prep_W(const float* __restrict__ W, short* __restrict__ Wb) {
    int frag = blockIdx.x;            // 128 blocks x 1 wave
    int l = threadIdx.x;              // 0..63
    int col = (frag >> 2) * 32 + (l & 31);
    int fb = (frag & 3) * 16 + ((l >> 5) * 8);
    short8 v;
#pragma unroll
    for (int t = 0; t < 8; ++t)
        v[t] = f2bf(W[(size_t)(fb + t) * NN + col]);
    *reinterpret_cast<short8*>(Wb + ((size_t)frag * 64 + l) * 8) = v;
}

// One wave = 64 edges = two 32-edge MFMA column groups sharing every
// W-register read (halves W L2 traffic vs 32 e/w). Per i: 4 W frags from
// L2 -> regs, bias as C-init, 2x4 chained mfma_32x32x16, relu+matvec in f32,
// one shfl_xor(32) per edge group. NO LDS, NO barriers — compiler free to
// pipeline i+1 loads under i compute. Output: float4 per lane per 4-i quad,
// half-wave h stores edge group h directly to global.
__global__ __launch_bounds__(128, 2) void mp_main(
    const float* __restrict__ node, const float* __restrict__ edge,
    const short* __restrict__ Wb, const float* __restrict__ bias,
    float* __restrict__ out) {
    const int tid = threadIdx.x;
    const int wid = tid >> 6;                 // 0..1
    const int l   = tid & 63;
    const int e32 = l & 31;                   // lane's edge col (MFMA N)
    const int h   = l >> 5;                   // lane half (k-group / row offset)
    const int eb  = blockIdx.x * 128 + wid * 64;

    // ---- edge B-fragments ef[eg][ks]: k = h*8+t -> edge[e, ks*16 + h*8 + t]
    // ---- node values nv[eg][q*4+rr]: acc reg r=q*4+rr -> j = q*8 + h*4 + rr
    short8 ef[2][4];
    float  nv[2][16];
#pragma unroll
    for (int eg = 0; eg < 2; ++eg) {
        const float* erow = edge + (size_t)(eb + eg * 32 + e32) * EDGE_DIM;
#pragma unroll
        for (int ks = 0; ks < 4; ++ks) {
            f32x4 a = *reinterpret_cast<const f32x4*>(erow + ks * 16 + h * 8);
            f32x4 b = *reinterpret_cast<const f32x4*>(erow + ks * 16 + h * 8 + 4);
            short8 v;
            v[0] = f2bf(a[0]); v[1] = f2bf(a[1]); v[2] = f2bf(a[2]); v[3] = f2bf(a[3]);
            v[4] = f2bf(b[0]); v[5] = f2bf(b[1]); v[6] = f2bf(b[2]); v[7] = f2bf(b[3]);
            ef[eg][ks] = v;
        }
        const float* nrow = node + (size_t)(eb + eg * 32 + e32) * NODE_DIM;
#pragma unroll
        for (int q = 0; q < 4; ++q) {
            f32x4 n = *reinterpret_cast<const f32x4*>(nrow + q * 8 + h * 4);
            nv[eg][q * 4 + 0] = n[0]; nv[eg][q * 4 + 1] = n[1];
            nv[eg][q * 4 + 2] = n[2]; nv[eg][q * 4 + 3] = n[3];
        }
    }

    // lane's output row: half-wave h owns edge group h
    float* orow = out + (size_t)(eb + h * 32 + e32) * NODE_DIM;

    for (int iq = 0; iq < 8; ++iq) {
        f32x4 vq;
#pragma unroll
        for (int r = 0; r < 4; ++r) {
            const int i = iq * 4 + r;
            const short* wp = Wb + (size_t)i * 2048 + l * 8;
            short8 w0 = *reinterpret_cast<const short8*>(wp + 0 * 512);
            short8 w1 = *reinterpret_cast<const short8*>(wp + 1 * 512);
            short8 w2 = *reinterpret_cast<const short8*>(wp + 2 * 512);
            short8 w3 = *reinterpret_cast<const short8*>(wp + 3 * 512);

            // bias as C-init (same for both edge groups): reg q*4+rr -> row q*8+h*4+rr
            f32x16 acc0, acc1;
#pragma unroll
            for (int q = 0; q < 4; ++q) {
                f32x4 bq = *reinterpret_cast<const f32x4*>(bias + i * 32 + q * 8 + h * 4);
                acc0[q * 4 + 0] = bq[0]; acc0[q * 4 + 1] = bq[1];
                acc0[q * 4 + 2] = bq[2]; acc0[q * 4 + 3] = bq[3];
            }
            acc1 = acc0;

            acc0 = __builtin_amdgcn_mfma_f32_32x32x16_bf16(w0, ef[0][0], acc0, 0, 0, 0);
            acc1 = __builtin_amdgcn_mfma_f32_32x32x16_bf16(w0, ef[1][0], acc1, 0, 0, 0);
            acc0 = __builtin_amdgcn_mfma_f32_32x32x16_bf16(w1, ef[0][1], acc0, 0, 0, 0);
            acc1 = __builtin_amdgcn_mfma_f32_32x32x16_bf16(w1, ef[1][1], acc1, 0, 0, 0);
            acc0 = __builtin_amdgcn_mfma_f32_32x32x16_bf16(w2, ef[0][2], acc0, 0, 0, 0);
            acc1 = __builtin_amdgcn_mfma_f32_32x32x16_bf16(w2, ef[1][2], acc1, 0, 0, 0);
            acc0 = __builtin_amdgcn_mfma_f32_32x32x16_bf16(w3, ef[0][3], acc0, 0, 0, 0);
            acc1 = __builtin_amdgcn_mfma_f32_32x32x16_bf16(w3, ef[1][3], acc1, 0, 0, 0);

            // relu + matvec: lane covers 16 of 32 j's; partner half via shfl_xor(32)
            float p0 = 0.f, p1 = 0.f;
#pragma unroll
            for (int rr = 0; rr < 16; ++rr) {
                p0 += fmaxf(acc0[rr], 0.f) * nv[0][rr];
                p1 += fmaxf(acc1[rr], 0.f) * nv[1][rr];
            }
            p0 += __shfl_xor(p0, 32);
            p1 += __shfl_xor(p1, 32);
            vq[r] = h ? p1 : p0;              // lane's edge = eb + h*32 + e32
        }
        *reinterpret_cast<f32x4*>(orow + iq * 4) = vq;   // msg[e, iq*4 .. +3]
    }
}

extern "C" void kernel_launch(void* const* d_in, const int* in_sizes, int n_in,
                              void* d_out, int out_size, void* d_ws, size_t ws_size,
                              hipStream_t stream) {
    const float* node = (const float*)d_in[0];  // [16,4096,32] f32
    const float* edge = (const float*)d_in[1];  // [16,4096,64] f32
    const float* W    = (const float*)d_in[2];  // [64,1024] f32
    const float* bias = (const float*)d_in[3];  // [1024] f32
    float* out = (float*)d_out;                 // [16,4096,32] f32
    short* Wb = (short*)d_ws;                   // 128 KB bf16 fragment-packed W

    prep_W<<<dim3(128), dim3(64), 0, stream>>>(W, Wb);
    mp_main<<<dim3(NROWS / 128), dim3(128), 0, stream>>>(node, edge, Wb, bias, out);
}

// Round 6
// 32.239 us; speedup vs baseline: 1.1840x; 1.0867x over previous
//
#include <hip/hip_runtime.h>
#include <hip/hip_bf16.h>

typedef __attribute__((ext_vector_type(8))) short short8;
typedef __attribute__((ext_vector_type(4))) float f32x4;
typedef __attribute__((ext_vector_type(16))) float f32x16;
typedef unsigned int u32;

#define NROWS 65536             // BATCH * N_EDGES
#define EDGE_DIM 64
#define NODE_DIM 32
#define NN 1024                 // NODE_DIM^2

__device__ __forceinline__ short f2bf(float f) {
    unsigned u = __builtin_bit_cast(unsigned, f);
    u += 0x7FFFu + ((u >> 16) & 1u);            // round-to-nearest-even
    return (short)(u >> 16);
}

// async 16B global->LDS copy (dest = wave-uniform base + lane*16)
__device__ __forceinline__ void gload_lds16(const void* g, void* l) {
    __builtin_amdgcn_global_load_lds(
        (const __attribute__((address_space(1))) u32*)g,
        (__attribute__((address_space(3))) u32*)l, 16, 0, 0);
}

// Pack W [64,1024] f32 -> bf16 A-operand fragments for mfma_f32_32x32x16_bf16.
// frag id = i*4 + ks (i = output row 0..31, ks = K-step 0..3).
// Wb[(frag*64 + l)*8 + t] = bf16(W[ks*16 + (l>>5)*8 + t, i*32 + (l&31)])
// (symmetric (lane-half,slot)->k map, identical to the B-operand pack; only
// the HW-verified C/D layout is load-bearing. Verified correct R2/R3/R5.)
__global__ void prep_W(const float* __restrict__ W, short* __restrict__ Wb) {
    int frag = blockIdx.x;            // 128 blocks x 1 wave
    int l = threadIdx.x;              // 0..63
    int col = (frag >> 2) * 32 + (l & 31);
    int fb = (frag & 3) * 16 + ((l >> 5) * 8);
    short8 v;
#pragma unroll
    for (int t = 0; t < 8; ++t)
        v[t] = f2bf(W[(size_t)(fb + t) * NN + col]);
    *reinterpret_cast<short8*>(Wb + ((size_t)frag * 64 + l) * 8) = v;
}

// 256 blocks x 4 waves x 64 edges. Whole packed W (128 KB) staged to LDS once
// via global_load_lds; ONE barrier; then a barrier-free i-loop: per i, 4
// conflict-free ds_read_b128 (W frags, shared by both 32-edge groups), bias
// as C-init (L1-hot global), 2x4 interleaved mfma_32x32x16 chains, epilogue
// with 4 independent partial accumulators per group, one shfl_xor(32) each.
__global__ __launch_bounds__(256) void mp_main(
    const float* __restrict__ node, const float* __restrict__ edge,
    const short* __restrict__ Wb, const float* __restrict__ bias,
    float* __restrict__ out) {
    __shared__ __align__(16) short ldsW[65536];   // 128 KB: full packed W

    const int tid = threadIdx.x;
    const int wid = tid >> 6;                 // 0..3
    const int l   = tid & 63;
    const int e32 = l & 31;                   // lane's edge col (MFMA N)
    const int h   = l >> 5;                   // lane half (k-group / row offset)
    const int eb  = blockIdx.x * 256 + wid * 64;

    // ---- per-lane inputs (issued before staging; barrier drains all) ----
    // ef[eg][ks]: k = h*8+t -> edge[e, ks*16 + h*8 + t]
    // nv[eg][q*4+rr]: acc reg r=q*4+rr -> j = q*8 + h*4 + rr
    short8 ef[2][4];
    float  nv[2][16];
#pragma unroll
    for (int eg = 0; eg < 2; ++eg) {
        const float* erow = edge + (size_t)(eb + eg * 32 + e32) * EDGE_DIM;
#pragma unroll
        for (int ks = 0; ks < 4; ++ks) {
            f32x4 a = *reinterpret_cast<const f32x4*>(erow + ks * 16 + h * 8);
            f32x4 b = *reinterpret_cast<const f32x4*>(erow + ks * 16 + h * 8 + 4);
            short8 v;
            v[0] = f2bf(a[0]); v[1] = f2bf(a[1]); v[2] = f2bf(a[2]); v[3] = f2bf(a[3]);
            v[4] = f2bf(b[0]); v[5] = f2bf(b[1]); v[6] = f2bf(b[2]); v[7] = f2bf(b[3]);
            ef[eg][ks] = v;
        }
        const float* nrow = node + (size_t)(eb + eg * 32 + e32) * NODE_DIM;
#pragma unroll
        for (int q = 0; q < 4; ++q) {
            f32x4 n = *reinterpret_cast<const f32x4*>(nrow + q * 8 + h * 4);
            nv[eg][q * 4 + 0] = n[0]; nv[eg][q * 4 + 1] = n[1];
            nv[eg][q * 4 + 2] = n[2]; nv[eg][q * 4 + 3] = n[3];
        }
    }

    // ---- stage full W: 32 x (256 lanes x 16 B) = 128 KB, coalesced from L2
#pragma unroll
    for (int k = 0; k < 32; ++k)
        gload_lds16(Wb + (size_t)(k * 256 + tid) * 8,
                    &ldsW[(size_t)k * 2048 + wid * 512]);
    __syncthreads();                          // the ONLY barrier

    // lane's output row: e = eb + l (h=0 -> eg0, h=1 -> eg1)
    float* orow = out + (size_t)(eb + l) * NODE_DIM;

    for (int iq = 0; iq < 8; ++iq) {
        f32x4 vq;
#pragma unroll
        for (int r = 0; r < 4; ++r) {
            const int i = iq * 4 + r;
            const short* wp = &ldsW[(size_t)i * 2048 + l * 8];
            short8 w0 = *reinterpret_cast<const short8*>(wp + 0 * 512);
            short8 w1 = *reinterpret_cast<const short8*>(wp + 1 * 512);
            short8 w2 = *reinterpret_cast<const short8*>(wp + 2 * 512);
            short8 w3 = *reinterpret_cast<const short8*>(wp + 3 * 512);

            // bias as C-init: reg q*4+rr -> row q*8 + h*4 + rr (L1-hot, 128 B/i)
            f32x16 acc0, acc1;
#pragma unroll
            for (int q = 0; q < 4; ++q) {
                f32x4 bq = *reinterpret_cast<const f32x4*>(bias + i * 32 + q * 8 + h * 4);
                acc0[q * 4 + 0] = bq[0]; acc0[q * 4 + 1] = bq[1];
                acc0[q * 4 + 2] = bq[2]; acc0[q * 4 + 3] = bq[3];
            }
            acc1 = acc0;

            acc0 = __builtin_amdgcn_mfma_f32_32x32x16_bf16(w0, ef[0][0], acc0, 0, 0, 0);
            acc1 = __builtin_amdgcn_mfma_f32_32x32x16_bf16(w0, ef[1][0], acc1, 0, 0, 0);
            acc0 = __builtin_amdgcn_mfma_f32_32x32x16_bf16(w1, ef[0][1], acc0, 0, 0, 0);
            acc1 = __builtin_amdgcn_mfma_f32_32x32x16_bf16(w1, ef[1][1], acc1, 0, 0, 0);
            acc0 = __builtin_amdgcn_mfma_f32_32x32x16_bf16(w2, ef[0][2], acc0, 0, 0, 0);
            acc1 = __builtin_amdgcn_mfma_f32_32x32x16_bf16(w2, ef[1][2], acc1, 0, 0, 0);
            acc0 = __builtin_amdgcn_mfma_f32_32x32x16_bf16(w3, ef[0][3], acc0, 0, 0, 0);
            acc1 = __builtin_amdgcn_mfma_f32_32x32x16_bf16(w3, ef[1][3], acc1, 0, 0, 0);

            // relu + matvec, 4 independent partials per group (chain depth 4)
            float s00 = 0.f, s01 = 0.f, s02 = 0.f, s03 = 0.f;
            float s10 = 0.f, s11 = 0.f, s12 = 0.f, s13 = 0.f;
#pragma unroll
            for (int rr = 0; rr < 4; ++rr) {
                s00 += fmaxf(acc0[rr],      0.f) * nv[0][rr];
                s01 += fmaxf(acc0[4 + rr],  0.f) * nv[0][4 + rr];
                s02 += fmaxf(acc0[8 + rr],  0.f) * nv[0][8 + rr];
                s03 += fmaxf(acc0[12 + rr], 0.f) * nv[0][12 + rr];
                s10 += fmaxf(acc1[rr],      0.f) * nv[1][rr];
                s11 += fmaxf(acc1[4 + rr],  0.f) * nv[1][4 + rr];
                s12 += fmaxf(acc1[8 + rr],  0.f) * nv[1][8 + rr];
                s13 += fmaxf(acc1[12 + rr], 0.f) * nv[1][12 + rr];
            }
            float p0 = (s00 + s01) + (s02 + s03);
            float p1 = (s10 + s11) + (s12 + s13);
            p0 += __shfl_xor(p0, 32);
            p1 += __shfl_xor(p1, 32);
            vq[r] = h ? p1 : p0;              // lane's edge = eb + l
        }
        *reinterpret_cast<f32x4*>(orow + iq * 4) = vq;   // msg[e, iq*4 .. +3]
    }
}

extern "C" void kernel_launch(void* const* d_in, const int* in_sizes, int n_in,
                              void* d_out, int out_size, void* d_ws, size_t ws_size,
                              hipStream_t stream) {
    const float* node = (const float*)d_in[0];  // [16,4096,32] f32
    const float* edge = (const float*)d_in[1];  // [16,4096,64] f32
    const float* W    = (const float*)d_in[2];  // [64,1024] f32
    const float* bias = (const float*)d_in[3];  // [1024] f32
    float* out = (float*)d_out;                 // [16,4096,32] f32
    short* Wb = (short*)d_ws;                   // 128 KB bf16 fragment-packed W

    prep_W<<<dim3(128), dim3(64), 0, stream>>>(W, Wb);
    mp_main<<<dim3(NROWS / 256), dim3(256), 0, stream>>>(node, edge, Wb, bias, out);
}

// Round 7
// 27.494 us; speedup vs baseline: 1.3883x; 1.1726x over previous
//
#include <hip/hip_runtime.h>
#include <hip/hip_bf16.h>

typedef __attribute__((ext_vector_type(8))) short short8;
typedef __attribute__((ext_vector_type(4))) float f32x4;
typedef __attribute__((ext_vector_type(16))) float f32x16;
typedef unsigned int u32;

#define NROWS 65536             // BATCH * N_EDGES
#define EDGE_DIM 64
#define NODE_DIM 32
#define NN 1024                 // NODE_DIM^2

__device__ __forceinline__ short f2bf(float f) {
    unsigned u = __builtin_bit_cast(unsigned, f);
    u += 0x7FFFu + ((u >> 16) & 1u);            // round-to-nearest-even
    return (short)(u >> 16);
}

// async 16B global->LDS copy (dest = wave-uniform base + lane*16)
__device__ __forceinline__ void gload_lds16(const void* g, void* l) {
    __builtin_amdgcn_global_load_lds(
        (const __attribute__((address_space(1))) u32*)g,
        (__attribute__((address_space(3))) u32*)l, 16, 0, 0);
}

// Pack W [64,1024] f32 -> bf16 A-operand fragments for mfma_f32_32x32x16_bf16.
// frag id = i*4 + ks (i = output row 0..31, ks = K-step 0..3).
// Wb[(frag*64 + l)*8 + t] = bf16(W[ks*16 + (l>>5)*8 + t, i*32 + (l&31)])
// (symmetric (lane-half,slot)->k map, identical to the B-operand pack; only
// the HW-verified C/D layout is load-bearing. Verified correct R2/R3/R5/R6.)
__global__ void prep_W(const float* __restrict__ W, short* __restrict__ Wb) {
    int frag = blockIdx.x;            // 128 blocks x 1 wave
    int l = threadIdx.x;              // 0..63
    int col = (frag >> 2) * 32 + (l & 31);
    int fb = (frag & 3) * 16 + ((l >> 5) * 8);
    short8 v;
#pragma unroll
    for (int t = 0; t < 8; ++t)
        v[t] = f2bf(W[(size_t)(fb + t) * NN + col]);
    *reinterpret_cast<short8*>(Wb + ((size_t)frag * 64 + l) * 8) = v;
}

// 256 blocks x 8 waves x 32 edges (512 threads; LDS 128 KB -> 1 block/CU but
// 2 waves/SIMD, double R6's TLP). Whole packed W staged to LDS once via
// global_load_lds (16 x 8 KB), ONE barrier, then a barrier-free i-loop:
// per i, 4 conflict-free ds_read_b128 (W frags), bias as C-init (L1-hot),
// one 4-chain mfma_32x32x16 per i (r=0..3 chains independent -> ILP),
// relu+matvec epilogue with 4 independent partials, one shfl_xor(32),
// direct half-wave float4 stores (no LDS restage).
__global__ __launch_bounds__(512) void mp_main(
    const float* __restrict__ node, const float* __restrict__ edge,
    const short* __restrict__ Wb, const float* __restrict__ bias,
    float* __restrict__ out) {
    __shared__ __align__(16) short ldsW[65536];   // 128 KB: full packed W

    const int tid = threadIdx.x;
    const int wid = tid >> 6;                 // 0..7
    const int l   = tid & 63;
    const int e32 = l & 31;                   // lane's edge col (MFMA N)
    const int h   = l >> 5;                   // lane half (k-group / row offset)
    const int eb  = blockIdx.x * 256 + wid * 32;
    const int e   = eb + e32;

    // ---- per-lane inputs (issued before staging; barrier drains all) ----
    // ef[ks]: k = h*8+t -> edge[e, ks*16 + h*8 + t]
    // nv[q*4+rr]: acc reg r=q*4+rr -> j = q*8 + h*4 + rr
    short8 ef[4];
    float  nv[16];
    const float* erow = edge + (size_t)e * EDGE_DIM;
#pragma unroll
    for (int ks = 0; ks < 4; ++ks) {
        f32x4 a = *reinterpret_cast<const f32x4*>(erow + ks * 16 + h * 8);
        f32x4 b = *reinterpret_cast<const f32x4*>(erow + ks * 16 + h * 8 + 4);
        short8 v;
        v[0] = f2bf(a[0]); v[1] = f2bf(a[1]); v[2] = f2bf(a[2]); v[3] = f2bf(a[3]);
        v[4] = f2bf(b[0]); v[5] = f2bf(b[1]); v[6] = f2bf(b[2]); v[7] = f2bf(b[3]);
        ef[ks] = v;
    }
    const float* nrow = node + (size_t)e * NODE_DIM;
#pragma unroll
    for (int q = 0; q < 4; ++q) {
        f32x4 n = *reinterpret_cast<const f32x4*>(nrow + q * 8 + h * 4);
        nv[q * 4 + 0] = n[0]; nv[q * 4 + 1] = n[1];
        nv[q * 4 + 2] = n[2]; nv[q * 4 + 3] = n[3];
    }

    // ---- stage full W: 16 x (512 lanes x 16 B) = 128 KB, linear mapping ----
#pragma unroll
    for (int k = 0; k < 16; ++k)
        gload_lds16(Wb + (size_t)(k * 512 + tid) * 8,
                    &ldsW[(size_t)k * 4096 + wid * 512]);
    __syncthreads();                          // the ONLY barrier

    // lane's output row (lanes 0..31 store; index clamped to stay in-bounds)
    float* orow = out + (size_t)(eb + (l & 31)) * NODE_DIM;

#pragma unroll 2
    for (int iq = 0; iq < 8; ++iq) {
        f32x4 vq;
#pragma unroll
        for (int r = 0; r < 4; ++r) {
            const int i = iq * 4 + r;
            const short* wp = &ldsW[(size_t)i * 2048 + l * 8];
            short8 w0 = *reinterpret_cast<const short8*>(wp + 0 * 512);
            short8 w1 = *reinterpret_cast<const short8*>(wp + 1 * 512);
            short8 w2 = *reinterpret_cast<const short8*>(wp + 2 * 512);
            short8 w3 = *reinterpret_cast<const short8*>(wp + 3 * 512);

            // bias as C-init: reg q*4+rr -> row q*8 + h*4 + rr (L1-hot)
            f32x16 acc;
#pragma unroll
            for (int q = 0; q < 4; ++q) {
                f32x4 bq = *reinterpret_cast<const f32x4*>(bias + i * 32 + q * 8 + h * 4);
                acc[q * 4 + 0] = bq[0]; acc[q * 4 + 1] = bq[1];
                acc[q * 4 + 2] = bq[2]; acc[q * 4 + 3] = bq[3];
            }

            acc = __builtin_amdgcn_mfma_f32_32x32x16_bf16(w0, ef[0], acc, 0, 0, 0);
            acc = __builtin_amdgcn_mfma_f32_32x32x16_bf16(w1, ef[1], acc, 0, 0, 0);
            acc = __builtin_amdgcn_mfma_f32_32x32x16_bf16(w2, ef[2], acc, 0, 0, 0);
            acc = __builtin_amdgcn_mfma_f32_32x32x16_bf16(w3, ef[3], acc, 0, 0, 0);

            // relu + matvec, 4 independent partials (chain depth 4)
            float s0 = 0.f, s1 = 0.f, s2 = 0.f, s3 = 0.f;
#pragma unroll
            for (int rr = 0; rr < 4; ++rr) {
                s0 += fmaxf(acc[rr],      0.f) * nv[rr];
                s1 += fmaxf(acc[4 + rr],  0.f) * nv[4 + rr];
                s2 += fmaxf(acc[8 + rr],  0.f) * nv[8 + rr];
                s3 += fmaxf(acc[12 + rr], 0.f) * nv[12 + rr];
            }
            float p = (s0 + s1) + (s2 + s3);
            p += __shfl_xor(p, 32);           // add partner half's 16 j's
            vq[r] = p;
        }
        if (l < 32)
            *reinterpret_cast<f32x4*>(orow + iq * 4) = vq;  // msg[e, iq*4..+3]
    }
}

extern "C" void kernel_launch(void* const* d_in, const int* in_sizes, int n_in,
                              void* d_out, int out_size, void* d_ws, size_t ws_size,
                              hipStream_t stream) {
    const float* node = (const float*)d_in[0];  // [16,4096,32] f32
    const float* edge = (const float*)d_in[1];  // [16,4096,64] f32
    const float* W    = (const float*)d_in[2];  // [64,1024] f32
    const float* bias = (const float*)d_in[3];  // [1024] f32
    float* out = (float*)d_out;                 // [16,4096,32] f32
    short* Wb = (short*)d_ws;                   // 128 KB bf16 fragment-packed W

    prep_W<<<dim3(128), dim3(64), 0, stream>>>(W, Wb);
    mp_main<<<dim3(NROWS / 256), dim3(512), 0, stream>>>(node, edge, Wb, bias, out);
}